// Round 1
// baseline (657.806 us; speedup 1.0000x reference)
//
#include <hip/hip_runtime.h>
#include <math.h>

#define MAX_T 128

__global__ __launch_bounds__(256) void sde_kernel(
    const float* __restrict__ y0,
    const float* __restrict__ ts,
    const float* __restrict__ noise,
    const float* __restrict__ theta_p,
    float* __restrict__ out,
    int n4, int T)
{
    // Per-step uniform constants, computed once per block, broadcast from LDS.
    __shared__ float s_sin[MAX_T], s_cos[MAX_T], s_dt[MAX_T], s_sqdt[MAX_T];
    int tid = threadIdx.x;
    if (tid < T - 1) {
        float t  = ts[tid];
        float dt = ts[tid + 1] - t;
        s_sin[tid]  = sinf(t);
        s_cos[tid]  = cosf(t);
        s_dt[tid]   = dt;
        s_sqdt[tid] = sqrtf(dt);
    }
    float theta = theta_p[0];
    __syncthreads();

    int idx = blockIdx.x * blockDim.x + threadIdx.x;
    if (idx >= n4) return;

    const float4* __restrict__ y0v  = (const float4*)y0;
    const float4* __restrict__ nv   = (const float4*)noise;
    float4* __restrict__       outv = (float4*)out;

    float4 y = y0v[idx];
    outv[idx] = y;                      // out[0] = y0

    // Prefetch first noise vector; keep one load in flight across each step.
    float4 z = nv[idx];
    for (int t = 0; t < T - 1; ++t) {
        float4 znext = make_float4(0.f, 0.f, 0.f, 0.f);
        if (t + 1 < T - 1)
            znext = nv[(size_t)(t + 1) * n4 + idx];

        float st = s_sin[t];
        float ct = s_cos[t];
        float dt = s_dt[t];
        float sq = s_sqdt[t];

        // y_next = y + (sin t + theta*y)*dt + 0.3*sigmoid(cos t * exp(-y))*sqrt(dt)*z
        #define STEP(c) { \
            float drift = st + theta * y.c; \
            float e   = __expf(-y.c); \
            float arg = ct * e; \
            float sig = __builtin_amdgcn_rcpf(1.0f + __expf(-arg)); \
            float diff = 0.3f * sig; \
            y.c = y.c + drift * dt + diff * sq * z.c; }
        STEP(x); STEP(y); STEP(z); STEP(w);
        #undef STEP

        outv[(size_t)(t + 1) * n4 + idx] = y;
        z = znext;
    }
}

extern "C" void kernel_launch(void* const* d_in, const int* in_sizes, int n_in,
                              void* d_out, int out_size, void* d_ws, size_t ws_size,
                              hipStream_t stream) {
    const float* y0    = (const float*)d_in[0];
    const float* ts    = (const float*)d_in[1];
    const float* noise = (const float*)d_in[2];
    const float* theta = (const float*)d_in[3];
    float* out = (float*)d_out;

    int n = in_sizes[0];      // B*D
    int T = in_sizes[1];      // number of timesteps
    int n4 = n / 4;           // float4 granularity (B*D divisible by 4)

    int block = 256;
    int grid = (n4 + block - 1) / block;
    sde_kernel<<<grid, block, 0, stream>>>(y0, ts, noise, theta, out, n4, T);
}